// Round 13
// baseline (2970.080 us; speedup 1.0000x reference)
//
#include <hip/hip_runtime.h>

#define HH 720
#define WW 1280
#define HWP (HH*WW)

static constexpr int NFRM = 4;
typedef _Float16 h2 __attribute__((ext_vector_type(2)));

__device__ __forceinline__ unsigned pkh(float a, float b) {
  return __builtin_bit_cast(unsigned, __builtin_amdgcn_cvt_pkrtz(a, b));
}
__device__ __forceinline__ int bswz(int lin) { return lin ^ ((lin >> 3) & 7); }

// ========== register-tiled 3x3 SAME conv: PX px/thread, 256-thr blocks (tile 16*PX x 16) ==========
template <int PX, int C0, int C1, int COUT, bool RELU>
__global__ __launch_bounds__(256) void conv3x3_v4(const float* __restrict__ in0, long i0fs,
                                                  const float* __restrict__ in1, long i1fs,
                                                  const float* __restrict__ w,
                                                  const float* __restrict__ b,
                                                  float* __restrict__ out, long ofs) {
  constexpr int CIN = C0 + C1;
  constexpr int NBX = WW / (16 * PX);
  int fi = blockIdx.y;
  in0 += (size_t)fi * i0fs;
  out += (size_t)fi * ofs;
  const float* in1f = nullptr;
  if constexpr (C1 > 0) in1f = in1 + (size_t)fi * i1fs;

  int bx = blockIdx.x % NBX;
  int by = blockIdx.x / NBX;
  int tx = threadIdx.x & 15;
  int ty = threadIdx.x >> 4;     // 0..15
  int gx0 = bx * (16 * PX) + tx * PX;
  int gy  = by * 16 + ty;

  float acc[COUT][PX];
  #pragma unroll
  for (int co = 0; co < COUT; ++co) {
    float bv = b[co];
    #pragma unroll
    for (int px = 0; px < PX; ++px) acc[co][px] = bv;
  }

  const bool lok = (gx0 > 0);
  const bool rok = (gx0 + PX < WW);

  for (int c = 0; c < CIN; ++c) {
    const float* ch;
    if constexpr (C1 > 0)
      ch = (c < C0) ? (in0 + (size_t)c * HWP) : (in1f + (size_t)(c - C0) * HWP);
    else
      ch = in0 + (size_t)c * HWP;
    float r[3][PX + 2];
    #pragma unroll
    for (int ky = 0; ky < 3; ++ky) {
      int iy = gy + ky - 1;
      bool yok = (iy >= 0) && (iy < HH);
      const float* row = ch + (ptrdiff_t)iy * WW;
      if constexpr (PX == 4) {
        float4 a = yok ? *reinterpret_cast<const float4*>(row + gx0)
                       : make_float4(0.f, 0.f, 0.f, 0.f);
        r[ky][1] = a.x; r[ky][2] = a.y; r[ky][3] = a.z; r[ky][4] = a.w;
      } else {  // PX == 2
        float2 a = yok ? *reinterpret_cast<const float2*>(row + gx0)
                       : make_float2(0.f, 0.f);
        r[ky][1] = a.x; r[ky][2] = a.y;
      }
      r[ky][0]      = (yok && lok) ? row[gx0 - 1]  : 0.f;
      r[ky][PX + 1] = (yok && rok) ? row[gx0 + PX] : 0.f;
    }
    #pragma unroll
    for (int co = 0; co < COUT; ++co) {
      #pragma unroll
      for (int ky = 0; ky < 3; ++ky) {
        #pragma unroll
        for (int kx = 0; kx < 3; ++kx) {
          float wv = w[((co * CIN + c) * 3 + ky) * 3 + kx];
          #pragma unroll
          for (int px = 0; px < PX; ++px)
            acc[co][px] = fmaf(wv, r[ky][px + kx], acc[co][px]);
        }
      }
    }
  }

  size_t p = (size_t)gy * WW + gx0;
  #pragma unroll
  for (int co = 0; co < COUT; ++co) {
    if constexpr (PX == 4) {
      float4 o;
      o.x = RELU ? fmaxf(acc[co][0], 0.f) : acc[co][0];
      o.y = RELU ? fmaxf(acc[co][1], 0.f) : acc[co][1];
      o.z = RELU ? fmaxf(acc[co][2], 0.f) : acc[co][2];
      o.w = RELU ? fmaxf(acc[co][3], 0.f) : acc[co][3];
      *reinterpret_cast<float4*>(out + (size_t)co * HWP + p) = o;
    } else {
      float2 o;
      o.x = RELU ? fmaxf(acc[co][0], 0.f) : acc[co][0];
      o.y = RELU ? fmaxf(acc[co][1], 0.f) : acc[co][1];
      *reinterpret_cast<float2*>(out + (size_t)co * HWP + p) = o;
    }
  }
}

// ================= LCN: out = [lcn(color), color] (6 planes), 8 px/thread, frame-batched =================
__global__ __launch_bounds__(128) void lcn_v3(const float* __restrict__ x, long ifs,
                                              float* __restrict__ out, long ofs) {
  constexpr int NBX = WW / 128;
  int fi = blockIdx.y;
  const float* color = x + (size_t)fi * ifs;
  out += (size_t)fi * ofs;
  int bx = blockIdx.x % NBX;
  int by = blockIdx.x / NBX;
  int tx = threadIdx.x & 15;
  int ty = threadIdx.x >> 4;
  int gx0 = bx * 128 + tx * 8;
  int gy  = by * 8 + ty;
  const bool lok = (gx0 > 0);
  const bool rok = (gx0 + 8 < WW);
  size_t p = (size_t)gy * WW + gx0;

  #pragma unroll
  for (int c = 0; c < 3; ++c) {
    const float* ch = color + (size_t)c * HWP;
    float r[3][10];
    #pragma unroll
    for (int ky = 0; ky < 3; ++ky) {
      int iy = gy + ky - 1;
      bool yok = (iy >= 0) && (iy < HH);
      const float* row = ch + (ptrdiff_t)iy * WW;
      float4 a = yok ? *reinterpret_cast<const float4*>(row + gx0)
                     : make_float4(0.f, 0.f, 0.f, 0.f);
      float4 q = yok ? *reinterpret_cast<const float4*>(row + gx0 + 4)
                     : make_float4(0.f, 0.f, 0.f, 0.f);
      r[ky][0] = (yok && lok) ? row[gx0 - 1] : 0.f;
      r[ky][1] = a.x; r[ky][2] = a.y; r[ky][3] = a.z; r[ky][4] = a.w;
      r[ky][5] = q.x; r[ky][6] = q.y; r[ky][7] = q.z; r[ky][8] = q.w;
      r[ky][9] = (yok && rok) ? row[gx0 + 8] : 0.f;
    }
    float lcnv[8], cv[8];
    #pragma unroll
    for (int px = 0; px < 8; ++px) {
      float s = 0.f, s2 = 0.f;
      #pragma unroll
      for (int ky = 0; ky < 3; ++ky)
        #pragma unroll
        for (int kx = 0; kx < 3; ++kx) {
          float v = r[ky][px + kx];
          s += v; s2 = fmaf(v, v, s2);
        }
      float mean = s * (1.f / 9.f);
      float mean2 = s2 * (1.f / 9.f);
      float var = fmaxf(mean2 - mean * mean, 0.f);
      cv[px] = r[1][px + 1];
      lcnv[px] = (cv[px] - mean) * rsqrtf(var + 1e-5f);
    }
    #pragma unroll
    for (int h = 0; h < 2; ++h) {
      float4 o0 = make_float4(lcnv[4*h+0], lcnv[4*h+1], lcnv[4*h+2], lcnv[4*h+3]);
      float4 o1 = make_float4(cv[4*h+0], cv[4*h+1], cv[4*h+2], cv[4*h+3]);
      *reinterpret_cast<float4*>(out + (size_t)c * HWP + p + 4*h) = o0;
      *reinterpret_cast<float4*>(out + (size_t)(3 + c) * HWP + p + 4*h) = o1;
    }
  }
}

// ================= temporal blend: dyn = a*[color,hid] + (1-a)*temporal =================
__global__ __launch_bounds__(256) void blend_v3(const float* __restrict__ color,
                                                const float* __restrict__ hid,
                                                const float* __restrict__ temporal,
                                                const float* __restrict__ alpha,
                                                float* __restrict__ dyn, int first) {
  int i = (blockIdx.x * 256 + threadIdx.x) * 4;
  if (i >= HWP) return;
  if (first) {
    #pragma unroll
    for (int c = 0; c < 3; ++c)
      *reinterpret_cast<float4*>(dyn + (size_t)c * HWP + i) =
          *reinterpret_cast<const float4*>(color + (size_t)c * HWP + i);
    *reinterpret_cast<float4*>(dyn + 3 * (size_t)HWP + i) =
        *reinterpret_cast<const float4*>(hid + i);
  } else {
    float a = alpha[0];
    float om = 1.f - a;
    #pragma unroll
    for (int c = 0; c < 4; ++c) {
      const float* src = (c < 3) ? (color + (size_t)c * HWP) : hid;
      float4 cv = *reinterpret_cast<const float4*>(src + i);
      float4 tv = *reinterpret_cast<const float4*>(temporal + (size_t)c * HWP + i);
      float4 o;
      o.x = a * cv.x + om * tv.x;
      o.y = a * cv.y + om * tv.y;
      o.z = a * cv.z + om * tv.z;
      o.w = a * cv.w + om * tv.w;
      *reinterpret_cast<float4*>(dyn + (size_t)c * HWP + i) = o;
    }
  }
}

// ====== bilateral 7x7 v8: 32x16 tile, 256 thr, 2 px/thread, dyn f16 + feat f16 LDS (20.2 KB) ======
#define BC 38
#define BR 22
#define BNPX (BC*BR)   // 836
#define BPAD 840

template <bool OUT>
__global__ __launch_bounds__(256, 8) void bilateral_v8(const float* __restrict__ dyn,
                                                       const float* __restrict__ feat,
                                                       const float* __restrict__ scale,
                                                       float* __restrict__ outdyn,
                                                       const float* __restrict__ albedo,
                                                       float* __restrict__ outp) {
  __shared__ uint4 ft[BPAD];
  __shared__ uint2 dt[BPAD];
  int bx = blockIdx.x % 40;
  int by = blockIdx.x / 40;     // 0..44
  int tid = threadIdx.x;

  for (int i = tid; i < BNPX; i += 256) {
    int py = i / BC;
    int px = i - py * BC;
    int gy = min(max(by * 16 + py - 3, 0), HH - 1);
    int gx = min(max(bx * 32 + px - 3, 0), WW - 1);
    size_t g = (size_t)gy * WW + gx;
    int w = bswz(i);
    uint2 d;
    d.x = pkh(dyn[g],                 dyn[HWP + g]);
    d.y = pkh(dyn[2*(size_t)HWP + g], dyn[3*(size_t)HWP + g]);
    dt[w] = d;
    uint4 u;
    u.x = pkh(feat[g],                 feat[HWP + g]);
    u.y = pkh(feat[2*(size_t)HWP + g], feat[3*(size_t)HWP + g]);
    u.z = pkh(feat[4*(size_t)HWP + g], feat[5*(size_t)HWP + g]);
    u.w = pkh(feat[6*(size_t)HWP + g], feat[7*(size_t)HWP + g]);
    ft[w] = u;
  }
  __syncthreads();

  int txg = tid & 15;   // 2-px group
  int ty  = tid >> 4;   // 0..15

  float sv[8];
  #pragma unroll
  for (int c = 0; c < 8; ++c) sv[c] = scale[c];

  // center features (from LDS, consistent bits) ; sfc = s*fc ; A = sum sfc*fc
  float sfc[2][8], A[2];
  #pragma unroll
  for (int p = 0; p < 2; ++p) {
    int lin = (ty + 3) * BC + txg * 2 + 3 + p;
    uint4 u = ft[bswz(lin)];
    h2 a0 = __builtin_bit_cast(h2, u.x), a1 = __builtin_bit_cast(h2, u.y);
    h2 a2 = __builtin_bit_cast(h2, u.z), a3 = __builtin_bit_cast(h2, u.w);
    float fc[8] = {(float)a0[0], (float)a0[1], (float)a1[0], (float)a1[1],
                   (float)a2[0], (float)a2[1], (float)a3[0], (float)a3[1]};
    float aa = 0.f;
    #pragma unroll
    for (int c = 0; c < 8; ++c) {
      sfc[p][c] = sv[c] * fc[c];
      aa = fmaf(sfc[p][c], fc[c], aa);
    }
    A[p] = aa;
  }

  float acc[2][4], ws2[2];
  #pragma unroll
  for (int p = 0; p < 2; ++p) {
    ws2[p] = 0.f;
    acc[p][0] = acc[p][1] = acc[p][2] = acc[p][3] = 0.f;
  }

  for (int dy = 0; dy < 7; ++dy) {
    int rowb = (ty + dy) * BC + txg * 2;
    #pragma unroll
    for (int dx = 0; dx < 8; ++dx) {
      int w = bswz(rowb + dx);
      uint2 du = dt[w];
      uint4 u = ft[w];
      h2 d01 = __builtin_bit_cast(h2, du.x), d23 = __builtin_bit_cast(h2, du.y);
      h2 a0 = __builtin_bit_cast(h2, u.x), a1 = __builtin_bit_cast(h2, u.y);
      h2 a2 = __builtin_bit_cast(h2, u.z), a3 = __builtin_bit_cast(h2, u.w);
      float f[8] = {(float)a0[0], (float)a0[1], (float)a1[0], (float)a1[1],
                    (float)a2[0], (float)a2[1], (float)a3[0], (float)a3[1]};
      float B = 0.f;
      #pragma unroll
      for (int c = 0; c < 8; ++c) B = fmaf(sv[c] * f[c], f[c], B);
      float dv0 = (float)d01[0], dv1 = (float)d01[1];
      float dv2 = (float)d23[0], dv3 = (float)d23[1];
      #pragma unroll
      for (int p = 0; p < 2; ++p) {
        if (dx - p >= 0 && dx - p <= 6) {   // compile-time pruned
          float C = 0.f;
          #pragma unroll
          for (int c = 0; c < 8; ++c) C = fmaf(sfc[p][c], f[c], C);
          float e = fmaf(-2.f, C, A[p] + B);
          float wgt = __expf(-e);
          acc[p][0] = fmaf(wgt, dv0, acc[p][0]);
          acc[p][1] = fmaf(wgt, dv1, acc[p][1]);
          acc[p][2] = fmaf(wgt, dv2, acc[p][2]);
          acc[p][3] = fmaf(wgt, dv3, acc[p][3]);
          ws2[p] += wgt;
        }
      }
    }
  }

  int gy = by * 16 + ty;
  int gx0 = bx * 32 + txg * 2;
  size_t p0 = (size_t)gy * WW + gx0;
  float inv0 = 1.f / (ws2[0] + 1e-8f);
  float inv1 = 1.f / (ws2[1] + 1e-8f);
  #pragma unroll
  for (int c = 0; c < 4; ++c) {
    float2 o = make_float2(acc[0][c] * inv0, acc[1][c] * inv1);
    *reinterpret_cast<float2*>(outdyn + (size_t)c * HWP + p0) = o;
    if (OUT && c < 3) {
      float2 al = *reinterpret_cast<const float2*>(albedo + (size_t)c * HWP + p0);
      float2 oo = make_float2(o.x * al.x, o.y * al.y);
      *reinterpret_cast<float2*>(outp + (size_t)c * HWP + p0) = oo;
    }
  }
}

extern "C" void kernel_launch(void* const* d_in, const int* in_sizes, int n_in,
                              void* d_out, int out_size, void* d_ws, size_t ws_size,
                              hipStream_t stream) {
  const float* x          = (const float*)d_in[0];
  const float* alpha      = (const float*)d_in[1];
  const float* cr_w0      = (const float*)d_in[2];
  const float* cr_b0      = (const float*)d_in[3];
  const float* cr_w1      = (const float*)d_in[4];
  const float* cr_b1      = (const float*)d_in[5];
  const float* cr_w2      = (const float*)d_in[6];
  const float* cr_b2      = (const float*)d_in[7];
  const float* hs_w0      = (const float*)d_in[8];
  const float* hs_b0      = (const float*)d_in[9];
  const float* hs_w1      = (const float*)d_in[10];
  const float* hs_b1      = (const float*)d_in[11];
  const float* hs_w2      = (const float*)d_in[12];
  const float* hs_b2      = (const float*)d_in[13];
  const float* filt_w     = (const float*)d_in[14];
  const float* filt_b     = (const float*)d_in[15];
  const float* filt_scale = (const float*)d_in[16];

  float* out = (float*)d_out;
  float* ws  = (float*)d_ws;
  const size_t P = (size_t)HWP;

  bool batched = ws_size >= (size_t)108 * P * sizeof(float);
  float *bufA, *bufB, *dynT, *dynA, *dynB, *hid, *feat;
  if (batched) {
    bufA = ws;            bufB = ws + 48 * P;
    dynT = ws + 96 * P;   dynA = ws + 100 * P;  dynB = ws + 104 * P;
  } else {
    bufA = ws;            bufB = ws + 12 * P;
    dynT = ws + 24 * P;   dynA = ws + 28 * P;   dynB = ws + 32 * P;
  }
  hid  = bufA;   // CNN ping-pong dead by the time hidden is written
  feat = bufB;   // free during filter loop

  const int NB8 = (WW / 128) * (HH / 8);   // 900  (PX=8 lcn, 128 thr)
  const int NBC = (WW / 64)  * (HH / 16);  // 900  (PX=4 conv, 256 thr, tile 64x16)
  const int NBF = (WW / 32)  * (HH / 16);  // 1800 (PX=2 filter conv, tile 32x16)
  const int NBE = HWP / (256 * 4);         // 900
  const int NBB = (WW / 32)  * (HH / 16);  // 1800

  if (batched) {
    dim3 g8(NB8, NFRM), gc(NBC, NFRM);
    lcn_v3<<<g8, 128, 0, stream>>>(x, 12 * P, bufA, 6 * P);
    conv3x3_v4<4, 6, 0, 6,  true ><<<gc, 256, 0, stream>>>(bufA, 6 * P,  nullptr, 0, cr_w0, cr_b0, bufB, 6 * P);
    conv3x3_v4<4, 6, 0, 12, true ><<<gc, 256, 0, stream>>>(bufB, 6 * P,  nullptr, 0, cr_w1, cr_b1, bufA, 12 * P);
    conv3x3_v4<4, 12, 0, 3, false><<<gc, 256, 0, stream>>>(bufA, 12 * P, nullptr, 0, cr_w2, cr_b2, bufB, 3 * P);
    conv3x3_v4<4, 3, 9, 12, true ><<<gc, 256, 0, stream>>>(bufB, 3 * P,  x + 3 * P, 12 * P, hs_w0, hs_b0, bufA, 12 * P);
    conv3x3_v4<4, 12, 0, 12, true><<<gc, 256, 0, stream>>>(bufA, 12 * P, nullptr, 0, hs_w1, hs_b1, bufB, 12 * P);
    conv3x3_v4<4, 12, 0, 1, false><<<gc, 256, 0, stream>>>(bufB, 12 * P, nullptr, 0, hs_w2, hs_b2, hid, P);
  }

  for (int f = 0; f < NFRM; ++f) {
    const float* frame  = x + (size_t)f * 12 * P;
    const float* fixedp = frame + 3 * P;

    if (!batched) {
      dim3 g8(NB8, 1), gc(NBC, 1);
      lcn_v3<<<g8, 128, 0, stream>>>(frame, 0, bufA, 0);
      conv3x3_v4<4, 6, 0, 6,  true ><<<gc, 256, 0, stream>>>(bufA, 0, nullptr, 0, cr_w0, cr_b0, bufB, 0);
      conv3x3_v4<4, 6, 0, 12, true ><<<gc, 256, 0, stream>>>(bufB, 0, nullptr, 0, cr_w1, cr_b1, bufA, 0);
      conv3x3_v4<4, 12, 0, 3, false><<<gc, 256, 0, stream>>>(bufA, 0, nullptr, 0, cr_w2, cr_b2, bufB, 0);
      conv3x3_v4<4, 3, 9, 12, true ><<<gc, 256, 0, stream>>>(bufB, 0, fixedp, 0, hs_w0, hs_b0, bufA, 0);
      conv3x3_v4<4, 12, 0, 12, true><<<gc, 256, 0, stream>>>(bufA, 0, nullptr, 0, hs_w1, hs_b1, bufB, 0);
      conv3x3_v4<4, 12, 0, 1, false><<<gc, 256, 0, stream>>>(bufB, 0, nullptr, 0, hs_w2, hs_b2, hid, 0);
    }

    const float* hidf = batched ? (hid + (size_t)f * P) : hid;
    blend_v3<<<NBE, 256, 0, stream>>>(frame, hidf, dynT, alpha, dynA, f == 0 ? 1 : 0);

    float* cur = dynA;
    float* nxt = dynB;
    for (int k = 0; k < 5; ++k) {
      conv3x3_v4<2, 4, 9, 8, false><<<dim3(NBF, 1), 256, 0, stream>>>(
          cur, 0, fixedp, 0, filt_w + (size_t)k * 8 * 13 * 9, filt_b + k * 8, feat, 0);
      const float* sk = filt_scale + k * 8;
      if (k < 4) {
        bilateral_v8<false><<<NBB, 256, 0, stream>>>(cur, feat, sk, nxt, nullptr, nullptr);
        float* t = cur; cur = nxt; nxt = t;
      } else {
        bilateral_v8<true><<<NBB, 256, 0, stream>>>(cur, feat, sk, dynT,
                                                    fixedp, out + (size_t)f * 3 * P);
      }
    }
  }
}

// Round 14
// 2682.503 us; speedup vs baseline: 1.1072x; 1.1072x over previous
//
#include <hip/hip_runtime.h>

#define HH 720
#define WW 1280
#define HWP (HH*WW)
#define HPW (WW/2)      // packed dwords per row
#define HP  (HWP/2)     // packed dwords per plane

static constexpr int NFRM = 4;
typedef _Float16 h2 __attribute__((ext_vector_type(2)));

__device__ __forceinline__ unsigned pkh(float a, float b) {
  return __builtin_bit_cast(unsigned, __builtin_amdgcn_cvt_pkrtz(a, b));
}
__device__ __forceinline__ int bswz(int lin) { return lin ^ ((lin >> 3) & 7); }
__device__ __forceinline__ float lo16(unsigned u) { h2 v = __builtin_bit_cast(h2, u); return (float)v[0]; }
__device__ __forceinline__ float hi16(unsigned u) { h2 v = __builtin_bit_cast(h2, u); return (float)v[1]; }

// ===== packed-uint 3x3 SAME conv: 4 px/thread, tile 64x16, 256 thr; C0 packed planes + C1 f32 planes =====
template <int C0, int C1, int COUT, bool RELU>
__global__ __launch_bounds__(256) void conv_pp(const unsigned* __restrict__ in0, long i0fs,
                                               const float* __restrict__ in1, long i1fs,
                                               const float* __restrict__ w,
                                               const float* __restrict__ b,
                                               unsigned* __restrict__ out, long ofs) {
  constexpr int CIN = C0 + C1;
  constexpr int NBX = WW / 64;   // 20
  int fi = blockIdx.y;
  in0 += (size_t)fi * i0fs;
  out += (size_t)fi * ofs;
  const float* in1f = nullptr;
  if constexpr (C1 > 0) in1f = in1 + (size_t)fi * i1fs;

  int bx = blockIdx.x % NBX;
  int by = blockIdx.x / NBX;
  int tx = threadIdx.x & 15;
  int ty = threadIdx.x >> 4;
  int gx0 = bx * 64 + tx * 4;
  int gy  = by * 16 + ty;
  int D   = gx0 >> 1;

  float acc[COUT][4];
  #pragma unroll
  for (int co = 0; co < COUT; ++co) {
    float bv = b[co];
    #pragma unroll
    for (int px = 0; px < 4; ++px) acc[co][px] = bv;
  }

  const bool lok = (gx0 > 0);
  const bool rok = (gx0 + 4 < WW);

  float r[3][6];
  for (int c = 0; c < C0; ++c) {
    const unsigned* ch = in0 + (size_t)c * HP;
    #pragma unroll
    for (int ky = 0; ky < 3; ++ky) {
      int iy = gy + ky - 1;
      bool yok = (iy >= 0) && (iy < HH);
      const unsigned* row = ch + (ptrdiff_t)iy * HPW;
      unsigned um = (yok && lok) ? row[D - 1] : 0u;
      uint2 uc = yok ? *reinterpret_cast<const uint2*>(row + D) : make_uint2(0u, 0u);
      unsigned up = (yok && rok) ? row[D + 2] : 0u;
      r[ky][0] = hi16(um);
      r[ky][1] = lo16(uc.x); r[ky][2] = hi16(uc.x);
      r[ky][3] = lo16(uc.y); r[ky][4] = hi16(uc.y);
      r[ky][5] = lo16(up);
    }
    #pragma unroll
    for (int co = 0; co < COUT; ++co) {
      #pragma unroll
      for (int ky = 0; ky < 3; ++ky) {
        #pragma unroll
        for (int kx = 0; kx < 3; ++kx) {
          float wv = w[((co * CIN + c) * 3 + ky) * 3 + kx];
          #pragma unroll
          for (int px = 0; px < 4; ++px)
            acc[co][px] = fmaf(wv, r[ky][px + kx], acc[co][px]);
        }
      }
    }
  }
  if constexpr (C1 > 0) {
    for (int c = 0; c < C1; ++c) {
      const float* ch = in1f + (size_t)c * HWP;
      #pragma unroll
      for (int ky = 0; ky < 3; ++ky) {
        int iy = gy + ky - 1;
        bool yok = (iy >= 0) && (iy < HH);
        const float* row = ch + (ptrdiff_t)iy * WW;
        float4 a = yok ? *reinterpret_cast<const float4*>(row + gx0)
                       : make_float4(0.f, 0.f, 0.f, 0.f);
        r[ky][1] = a.x; r[ky][2] = a.y; r[ky][3] = a.z; r[ky][4] = a.w;
        r[ky][0] = (yok && lok) ? row[gx0 - 1] : 0.f;
        r[ky][5] = (yok && rok) ? row[gx0 + 4] : 0.f;
      }
      int cw = C0 + c;
      #pragma unroll
      for (int co = 0; co < COUT; ++co) {
        #pragma unroll
        for (int ky = 0; ky < 3; ++ky) {
          #pragma unroll
          for (int kx = 0; kx < 3; ++kx) {
            float wv = w[((co * CIN + cw) * 3 + ky) * 3 + kx];
            #pragma unroll
            for (int px = 0; px < 4; ++px)
              acc[co][px] = fmaf(wv, r[ky][px + kx], acc[co][px]);
          }
        }
      }
    }
  }

  size_t pD = (size_t)gy * HPW + D;
  #pragma unroll
  for (int co = 0; co < COUT; ++co) {
    float o0 = RELU ? fmaxf(acc[co][0], 0.f) : acc[co][0];
    float o1 = RELU ? fmaxf(acc[co][1], 0.f) : acc[co][1];
    float o2 = RELU ? fmaxf(acc[co][2], 0.f) : acc[co][2];
    float o3 = RELU ? fmaxf(acc[co][3], 0.f) : acc[co][3];
    uint2 o; o.x = pkh(o0, o1); o.y = pkh(o2, o3);
    *reinterpret_cast<uint2*>(out + (size_t)co * HP + pD) = o;
  }
}

// ===== f32->f32 3x3 SAME conv (filter conv): 4 px/thread, tile 64x16, 256 thr =====
template <int C0, int C1, int COUT, bool RELU>
__global__ __launch_bounds__(256) void conv3x3_v4(const float* __restrict__ in0,
                                                  const float* __restrict__ in1,
                                                  const float* __restrict__ w,
                                                  const float* __restrict__ b,
                                                  float* __restrict__ out) {
  constexpr int PX = 4;
  constexpr int CIN = C0 + C1;
  constexpr int NBX = WW / 64;
  int bx = blockIdx.x % NBX;
  int by = blockIdx.x / NBX;
  int tx = threadIdx.x & 15;
  int ty = threadIdx.x >> 4;
  int gx0 = bx * 64 + tx * PX;
  int gy  = by * 16 + ty;

  float acc[COUT][PX];
  #pragma unroll
  for (int co = 0; co < COUT; ++co) {
    float bv = b[co];
    #pragma unroll
    for (int px = 0; px < PX; ++px) acc[co][px] = bv;
  }

  const bool lok = (gx0 > 0);
  const bool rok = (gx0 + PX < WW);

  for (int c = 0; c < CIN; ++c) {
    const float* ch = (c < C0) ? (in0 + (size_t)c * HWP) : (in1 + (size_t)(c - C0) * HWP);
    float r[3][PX + 2];
    #pragma unroll
    for (int ky = 0; ky < 3; ++ky) {
      int iy = gy + ky - 1;
      bool yok = (iy >= 0) && (iy < HH);
      const float* row = ch + (ptrdiff_t)iy * WW;
      float4 a = yok ? *reinterpret_cast<const float4*>(row + gx0)
                     : make_float4(0.f, 0.f, 0.f, 0.f);
      r[ky][1] = a.x; r[ky][2] = a.y; r[ky][3] = a.z; r[ky][4] = a.w;
      r[ky][0]      = (yok && lok) ? row[gx0 - 1]  : 0.f;
      r[ky][PX + 1] = (yok && rok) ? row[gx0 + PX] : 0.f;
    }
    #pragma unroll
    for (int co = 0; co < COUT; ++co) {
      #pragma unroll
      for (int ky = 0; ky < 3; ++ky) {
        #pragma unroll
        for (int kx = 0; kx < 3; ++kx) {
          float wv = w[((co * CIN + c) * 3 + ky) * 3 + kx];
          #pragma unroll
          for (int px = 0; px < PX; ++px)
            acc[co][px] = fmaf(wv, r[ky][px + kx], acc[co][px]);
        }
      }
    }
  }

  size_t p = (size_t)gy * WW + gx0;
  #pragma unroll
  for (int co = 0; co < COUT; ++co) {
    float4 o;
    o.x = RELU ? fmaxf(acc[co][0], 0.f) : acc[co][0];
    o.y = RELU ? fmaxf(acc[co][1], 0.f) : acc[co][1];
    o.z = RELU ? fmaxf(acc[co][2], 0.f) : acc[co][2];
    o.w = RELU ? fmaxf(acc[co][3], 0.f) : acc[co][3];
    *reinterpret_cast<float4*>(out + (size_t)co * HWP + p) = o;
  }
}

// ===== LCN -> packed: out = [lcn(color), color] 6 packed planes, 8 px/thread =====
__global__ __launch_bounds__(128) void lcn_p(const float* __restrict__ x, long ifs,
                                             unsigned* __restrict__ out, long ofs) {
  constexpr int NBX = WW / 128;
  int fi = blockIdx.y;
  const float* color = x + (size_t)fi * ifs;
  out += (size_t)fi * ofs;
  int bx = blockIdx.x % NBX;
  int by = blockIdx.x / NBX;
  int tx = threadIdx.x & 15;
  int ty = threadIdx.x >> 4;
  int gx0 = bx * 128 + tx * 8;
  int gy  = by * 8 + ty;
  const bool lok = (gx0 > 0);
  const bool rok = (gx0 + 8 < WW);
  size_t pD = (size_t)gy * HPW + (gx0 >> 1);

  #pragma unroll
  for (int c = 0; c < 3; ++c) {
    const float* ch = color + (size_t)c * HWP;
    float r[3][10];
    #pragma unroll
    for (int ky = 0; ky < 3; ++ky) {
      int iy = gy + ky - 1;
      bool yok = (iy >= 0) && (iy < HH);
      const float* row = ch + (ptrdiff_t)iy * WW;
      float4 a = yok ? *reinterpret_cast<const float4*>(row + gx0)
                     : make_float4(0.f, 0.f, 0.f, 0.f);
      float4 q = yok ? *reinterpret_cast<const float4*>(row + gx0 + 4)
                     : make_float4(0.f, 0.f, 0.f, 0.f);
      r[ky][0] = (yok && lok) ? row[gx0 - 1] : 0.f;
      r[ky][1] = a.x; r[ky][2] = a.y; r[ky][3] = a.z; r[ky][4] = a.w;
      r[ky][5] = q.x; r[ky][6] = q.y; r[ky][7] = q.z; r[ky][8] = q.w;
      r[ky][9] = (yok && rok) ? row[gx0 + 8] : 0.f;
    }
    float lcnv[8], cv[8];
    #pragma unroll
    for (int px = 0; px < 8; ++px) {
      float s = 0.f, s2 = 0.f;
      #pragma unroll
      for (int ky = 0; ky < 3; ++ky)
        #pragma unroll
        for (int kx = 0; kx < 3; ++kx) {
          float v = r[ky][px + kx];
          s += v; s2 = fmaf(v, v, s2);
        }
      float mean = s * (1.f / 9.f);
      float mean2 = s2 * (1.f / 9.f);
      float var = fmaxf(mean2 - mean * mean, 0.f);
      cv[px] = r[1][px + 1];
      lcnv[px] = (cv[px] - mean) * rsqrtf(var + 1e-5f);
    }
    uint4 u0, u1;
    u0.x = pkh(lcnv[0], lcnv[1]); u0.y = pkh(lcnv[2], lcnv[3]);
    u0.z = pkh(lcnv[4], lcnv[5]); u0.w = pkh(lcnv[6], lcnv[7]);
    u1.x = pkh(cv[0], cv[1]);     u1.y = pkh(cv[2], cv[3]);
    u1.z = pkh(cv[4], cv[5]);     u1.w = pkh(cv[6], cv[7]);
    *reinterpret_cast<uint4*>(out + (size_t)c * HP + pD) = u0;
    *reinterpret_cast<uint4*>(out + (size_t)(3 + c) * HP + pD) = u1;
  }
}

// ===== temporal blend: dyn = a*[color, hid(packed)] + (1-a)*temporal =====
__global__ __launch_bounds__(256) void blend_v5(const float* __restrict__ color,
                                                const unsigned* __restrict__ hid,
                                                const float* __restrict__ temporal,
                                                const float* __restrict__ alpha,
                                                float* __restrict__ dyn, int first) {
  int i = (blockIdx.x * 256 + threadIdx.x) * 4;
  if (i >= HWP) return;
  uint2 hu = *reinterpret_cast<const uint2*>(hid + (i >> 1));
  float4 hv = make_float4(lo16(hu.x), hi16(hu.x), lo16(hu.y), hi16(hu.y));
  if (first) {
    #pragma unroll
    for (int c = 0; c < 3; ++c)
      *reinterpret_cast<float4*>(dyn + (size_t)c * HWP + i) =
          *reinterpret_cast<const float4*>(color + (size_t)c * HWP + i);
    *reinterpret_cast<float4*>(dyn + 3 * (size_t)HWP + i) = hv;
  } else {
    float a = alpha[0];
    float om = 1.f - a;
    #pragma unroll
    for (int c = 0; c < 4; ++c) {
      float4 cv = (c < 3) ? *reinterpret_cast<const float4*>(color + (size_t)c * HWP + i) : hv;
      float4 tv = *reinterpret_cast<const float4*>(temporal + (size_t)c * HWP + i);
      float4 o;
      o.x = a * cv.x + om * tv.x;
      o.y = a * cv.y + om * tv.y;
      o.z = a * cv.z + om * tv.z;
      o.w = a * cv.w + om * tv.w;
      *reinterpret_cast<float4*>(dyn + (size_t)c * HWP + i) = o;
    }
  }
}

// ====== bilateral 7x7 v5: 32x16 tile, 256 thr, 2 px/thread, dyn fp32 + feat f16 LDS ======
#define BC 38
#define BR 22
#define BNPX (BC*BR)   // 836
#define BPAD 840

template <bool OUT>
__global__ __launch_bounds__(256, 6) void bilateral_v5(const float* __restrict__ dyn,
                                                       const float* __restrict__ feat,
                                                       const float* __restrict__ scale,
                                                       float* __restrict__ outdyn,
                                                       const float* __restrict__ albedo,
                                                       float* __restrict__ outp) {
  __shared__ uint4  ft[BPAD];
  __shared__ float4 dt[BPAD];
  int bx = blockIdx.x % 40;
  int by = blockIdx.x / 40;     // 0..44
  int tid = threadIdx.x;

  for (int i = tid; i < BNPX; i += 256) {
    int py = i / BC;
    int px = i - py * BC;
    int gy = min(max(by * 16 + py - 3, 0), HH - 1);
    int gx = min(max(bx * 32 + px - 3, 0), WW - 1);
    size_t g = (size_t)gy * WW + gx;
    int w = bswz(i);
    dt[w] = make_float4(dyn[g], dyn[HWP + g], dyn[2*(size_t)HWP + g], dyn[3*(size_t)HWP + g]);
    uint4 u;
    u.x = pkh(feat[g],                 feat[HWP + g]);
    u.y = pkh(feat[2*(size_t)HWP + g], feat[3*(size_t)HWP + g]);
    u.z = pkh(feat[4*(size_t)HWP + g], feat[5*(size_t)HWP + g]);
    u.w = pkh(feat[6*(size_t)HWP + g], feat[7*(size_t)HWP + g]);
    ft[w] = u;
  }
  __syncthreads();

  int txg = tid & 15;   // 2-px group
  int ty  = tid >> 4;   // 0..15

  float sv[8];
  #pragma unroll
  for (int c = 0; c < 8; ++c) sv[c] = scale[c];

  float sfc[2][8], A[2];
  #pragma unroll
  for (int p = 0; p < 2; ++p) {
    int lin = (ty + 3) * BC + txg * 2 + 3 + p;
    uint4 u = ft[bswz(lin)];
    float fc[8] = {lo16(u.x), hi16(u.x), lo16(u.y), hi16(u.y),
                   lo16(u.z), hi16(u.z), lo16(u.w), hi16(u.w)};
    float aa = 0.f;
    #pragma unroll
    for (int c = 0; c < 8; ++c) {
      sfc[p][c] = sv[c] * fc[c];
      aa = fmaf(sfc[p][c], fc[c], aa);
    }
    A[p] = aa;
  }

  float acc[2][4], ws2[2];
  #pragma unroll
  for (int p = 0; p < 2; ++p) {
    ws2[p] = 0.f;
    acc[p][0] = acc[p][1] = acc[p][2] = acc[p][3] = 0.f;
  }

  for (int dy = 0; dy < 7; ++dy) {
    int rowb = (ty + dy) * BC + txg * 2;
    #pragma unroll
    for (int dx = 0; dx < 8; ++dx) {
      int w = bswz(rowb + dx);
      float4 dv = dt[w];
      uint4 u = ft[w];
      float f[8] = {lo16(u.x), hi16(u.x), lo16(u.y), hi16(u.y),
                    lo16(u.z), hi16(u.z), lo16(u.w), hi16(u.w)};
      float B = 0.f;
      #pragma unroll
      for (int c = 0; c < 8; ++c) B = fmaf(sv[c] * f[c], f[c], B);
      #pragma unroll
      for (int p = 0; p < 2; ++p) {
        if (dx - p >= 0 && dx - p <= 6) {   // compile-time pruned
          float C = 0.f;
          #pragma unroll
          for (int c = 0; c < 8; ++c) C = fmaf(sfc[p][c], f[c], C);
          float e = fmaf(-2.f, C, A[p] + B);
          float wgt = __expf(-e);
          acc[p][0] = fmaf(wgt, dv.x, acc[p][0]);
          acc[p][1] = fmaf(wgt, dv.y, acc[p][1]);
          acc[p][2] = fmaf(wgt, dv.z, acc[p][2]);
          acc[p][3] = fmaf(wgt, dv.w, acc[p][3]);
          ws2[p] += wgt;
        }
      }
    }
  }

  int gy = by * 16 + ty;
  int gx0 = bx * 32 + txg * 2;
  size_t p0 = (size_t)gy * WW + gx0;
  float inv0 = 1.f / (ws2[0] + 1e-8f);
  float inv1 = 1.f / (ws2[1] + 1e-8f);
  #pragma unroll
  for (int c = 0; c < 4; ++c) {
    float2 o = make_float2(acc[0][c] * inv0, acc[1][c] * inv1);
    *reinterpret_cast<float2*>(outdyn + (size_t)c * HWP + p0) = o;
    if (OUT && c < 3) {
      float2 al = *reinterpret_cast<const float2*>(albedo + (size_t)c * HWP + p0);
      float2 oo = make_float2(o.x * al.x, o.y * al.y);
      *reinterpret_cast<float2*>(outp + (size_t)c * HWP + p0) = oo;
    }
  }
}

extern "C" void kernel_launch(void* const* d_in, const int* in_sizes, int n_in,
                              void* d_out, int out_size, void* d_ws, size_t ws_size,
                              hipStream_t stream) {
  const float* x          = (const float*)d_in[0];
  const float* alpha      = (const float*)d_in[1];
  const float* cr_w0      = (const float*)d_in[2];
  const float* cr_b0      = (const float*)d_in[3];
  const float* cr_w1      = (const float*)d_in[4];
  const float* cr_b1      = (const float*)d_in[5];
  const float* cr_w2      = (const float*)d_in[6];
  const float* cr_b2      = (const float*)d_in[7];
  const float* hs_w0      = (const float*)d_in[8];
  const float* hs_b0      = (const float*)d_in[9];
  const float* hs_w1      = (const float*)d_in[10];
  const float* hs_b1      = (const float*)d_in[11];
  const float* hs_w2      = (const float*)d_in[12];
  const float* hs_b2      = (const float*)d_in[13];
  const float* filt_w     = (const float*)d_in[14];
  const float* filt_b     = (const float*)d_in[15];
  const float* filt_scale = (const float*)d_in[16];

  float* out = (float*)d_out;
  float* ws  = (float*)d_ws;
  const size_t P = (size_t)HWP;

  bool batched = ws_size >= (size_t)68 * P * sizeof(float);
  unsigned *pA, *pB;
  float *dynT, *dynA, *dynB, *feat;
  if (batched) {
    pA = (unsigned*)ws;                 // up to 48 packed planes (24P floats)
    pB = (unsigned*)(ws + 24 * P);      // up to 48 packed planes
    dynT = ws + 48 * P;  dynA = ws + 52 * P;  dynB = ws + 56 * P;
    feat = ws + 60 * P;                 // 8 f32 planes
  } else {
    pA = (unsigned*)ws;                 // 12 packed planes (6P floats)
    pB = (unsigned*)(ws + 6 * P);
    dynT = ws + 12 * P;  dynA = ws + 16 * P;  dynB = ws + 20 * P;
    feat = ws + 24 * P;
  }
  unsigned* hid = pA;   // last CNN output (1 packed plane/frame); pA ping-pong dead by then

  const int NB8 = (WW / 128) * (HH / 8);   // 900  (lcn, 128 thr)
  const int NBC = (WW / 64)  * (HH / 16);  // 900  (conv tiles, 256 thr)
  const int NBE = HWP / (256 * 4);         // 900
  const int NBB = (WW / 32)  * (HH / 16);  // 1800

  const int NF = batched ? NFRM : 1;
  dim3 g8(NB8, NF), gc(NBC, NF);
  long xs   = batched ? 12 * (long)P : 0;
  long s6   = batched ? 6  * (long)HP : 0;
  long s12  = batched ? 12 * (long)HP : 0;
  long s3   = batched ? 3  * (long)HP : 0;
  long s1   = batched ? (long)HP : 0;

  auto run_cnn = [&](const float* xin) {
    lcn_p<<<g8, 128, 0, stream>>>(xin, xs, pA, s6);
    conv_pp<6, 0, 6,  true ><<<gc, 256, 0, stream>>>(pA, s6,  nullptr, 0, cr_w0, cr_b0, pB, s6);
    conv_pp<6, 0, 12, true ><<<gc, 256, 0, stream>>>(pB, s6,  nullptr, 0, cr_w1, cr_b1, pA, s12);
    conv_pp<12, 0, 3, false><<<gc, 256, 0, stream>>>(pA, s12, nullptr, 0, cr_w2, cr_b2, pB, s3);
    conv_pp<3, 9, 12, true ><<<gc, 256, 0, stream>>>(pB, s3,  xin + 3 * P, xs, hs_w0, hs_b0, pA, s12);
    conv_pp<12, 0, 12, true><<<gc, 256, 0, stream>>>(pA, s12, nullptr, 0, hs_w1, hs_b1, pB, s12);
    conv_pp<12, 0, 1, false><<<gc, 256, 0, stream>>>(pB, s12, nullptr, 0, hs_w2, hs_b2, pA, s1);
  };

  if (batched) run_cnn(x);

  for (int f = 0; f < NFRM; ++f) {
    const float* frame  = x + (size_t)f * 12 * P;
    const float* fixedp = frame + 3 * P;

    if (!batched) run_cnn(frame);

    const unsigned* hidf = batched ? (hid + (size_t)f * HP) : hid;
    blend_v5<<<NBE, 256, 0, stream>>>(frame, hidf, dynT, alpha, dynA, f == 0 ? 1 : 0);

    float* cur = dynA;
    float* nxt = dynB;
    for (int k = 0; k < 5; ++k) {
      conv3x3_v4<4, 9, 8, false><<<dim3(NBC, 1), 256, 0, stream>>>(
          cur, fixedp, filt_w + (size_t)k * 8 * 13 * 9, filt_b + k * 8, feat);
      const float* sk = filt_scale + k * 8;
      if (k < 4) {
        bilateral_v5<false><<<NBB, 256, 0, stream>>>(cur, feat, sk, nxt, nullptr, nullptr);
        float* t = cur; cur = nxt; nxt = t;
      } else {
        bilateral_v5<true><<<NBB, 256, 0, stream>>>(cur, feat, sk, dynT,
                                                    fixedp, out + (size_t)f * 3 * P);
      }
    }
  }
}

// Round 15
// 2255.835 us; speedup vs baseline: 1.3166x; 1.1891x over previous
//
#include <hip/hip_runtime.h>

#define HH 720
#define WW 1280
#define HWP (HH*WW)

static constexpr int NFRM = 4;
typedef _Float16 h2 __attribute__((ext_vector_type(2)));

__device__ __forceinline__ unsigned pkh(float a, float b) {
  return __builtin_bit_cast(unsigned, __builtin_amdgcn_cvt_pkrtz(a, b));
}
__device__ __forceinline__ int bswz(int lin) { return lin ^ ((lin >> 3) & 7); }
__device__ __forceinline__ float lo16(unsigned u) { h2 v = __builtin_bit_cast(h2, u); return (float)v[0]; }
__device__ __forceinline__ float hi16(unsigned u) { h2 v = __builtin_bit_cast(h2, u); return (float)v[1]; }

// ========== register-tiled 3x3 SAME conv: PX=4 px/thread, 256-thr blocks (tile 64x16) ==========
template <int C0, int C1, int COUT, bool RELU>
__global__ __launch_bounds__(256) void conv3x3_v4(const float* __restrict__ in0, long i0fs,
                                                  const float* __restrict__ in1, long i1fs,
                                                  const float* __restrict__ w,
                                                  const float* __restrict__ b,
                                                  float* __restrict__ out, long ofs) {
  constexpr int PX = 4;
  constexpr int CIN = C0 + C1;
  constexpr int NBX = WW / 64;   // 20
  int fi = blockIdx.y;
  in0 += (size_t)fi * i0fs;
  out += (size_t)fi * ofs;
  const float* in1f = nullptr;
  if constexpr (C1 > 0) in1f = in1 + (size_t)fi * i1fs;

  int bx = blockIdx.x % NBX;
  int by = blockIdx.x / NBX;
  int tx = threadIdx.x & 15;
  int ty = threadIdx.x >> 4;     // 0..15
  int gx0 = bx * 64 + tx * PX;
  int gy  = by * 16 + ty;

  float acc[COUT][PX];
  #pragma unroll
  for (int co = 0; co < COUT; ++co) {
    float bv = b[co];
    #pragma unroll
    for (int px = 0; px < PX; ++px) acc[co][px] = bv;
  }

  const bool lok = (gx0 > 0);
  const bool rok = (gx0 + PX < WW);

  for (int c = 0; c < CIN; ++c) {
    const float* ch;
    if constexpr (C1 > 0)
      ch = (c < C0) ? (in0 + (size_t)c * HWP) : (in1f + (size_t)(c - C0) * HWP);
    else
      ch = in0 + (size_t)c * HWP;
    float r[3][PX + 2];
    #pragma unroll
    for (int ky = 0; ky < 3; ++ky) {
      int iy = gy + ky - 1;
      bool yok = (iy >= 0) && (iy < HH);
      const float* row = ch + (ptrdiff_t)iy * WW;
      float4 a = yok ? *reinterpret_cast<const float4*>(row + gx0)
                     : make_float4(0.f, 0.f, 0.f, 0.f);
      r[ky][1] = a.x; r[ky][2] = a.y; r[ky][3] = a.z; r[ky][4] = a.w;
      r[ky][0]      = (yok && lok) ? row[gx0 - 1]  : 0.f;
      r[ky][PX + 1] = (yok && rok) ? row[gx0 + PX] : 0.f;
    }
    #pragma unroll
    for (int co = 0; co < COUT; ++co) {
      #pragma unroll
      for (int ky = 0; ky < 3; ++ky) {
        #pragma unroll
        for (int kx = 0; kx < 3; ++kx) {
          float wv = w[((co * CIN + c) * 3 + ky) * 3 + kx];
          #pragma unroll
          for (int px = 0; px < PX; ++px)
            acc[co][px] = fmaf(wv, r[ky][px + kx], acc[co][px]);
        }
      }
    }
  }

  size_t p = (size_t)gy * WW + gx0;
  #pragma unroll
  for (int co = 0; co < COUT; ++co) {
    float4 o;
    o.x = RELU ? fmaxf(acc[co][0], 0.f) : acc[co][0];
    o.y = RELU ? fmaxf(acc[co][1], 0.f) : acc[co][1];
    o.z = RELU ? fmaxf(acc[co][2], 0.f) : acc[co][2];
    o.w = RELU ? fmaxf(acc[co][3], 0.f) : acc[co][3];
    *reinterpret_cast<float4*>(out + (size_t)co * HWP + p) = o;
  }
}

// ================= LCN: out = [lcn(color), color] (6 planes), 8 px/thread, frame-batched =================
__global__ __launch_bounds__(128) void lcn_v3(const float* __restrict__ x, long ifs,
                                              float* __restrict__ out, long ofs) {
  constexpr int NBX = WW / 128;
  int fi = blockIdx.y;
  const float* color = x + (size_t)fi * ifs;
  out += (size_t)fi * ofs;
  int bx = blockIdx.x % NBX;
  int by = blockIdx.x / NBX;
  int tx = threadIdx.x & 15;
  int ty = threadIdx.x >> 4;
  int gx0 = bx * 128 + tx * 8;
  int gy  = by * 8 + ty;
  const bool lok = (gx0 > 0);
  const bool rok = (gx0 + 8 < WW);
  size_t p = (size_t)gy * WW + gx0;

  #pragma unroll
  for (int c = 0; c < 3; ++c) {
    const float* ch = color + (size_t)c * HWP;
    float r[3][10];
    #pragma unroll
    for (int ky = 0; ky < 3; ++ky) {
      int iy = gy + ky - 1;
      bool yok = (iy >= 0) && (iy < HH);
      const float* row = ch + (ptrdiff_t)iy * WW;
      float4 a = yok ? *reinterpret_cast<const float4*>(row + gx0)
                     : make_float4(0.f, 0.f, 0.f, 0.f);
      float4 q = yok ? *reinterpret_cast<const float4*>(row + gx0 + 4)
                     : make_float4(0.f, 0.f, 0.f, 0.f);
      r[ky][0] = (yok && lok) ? row[gx0 - 1] : 0.f;
      r[ky][1] = a.x; r[ky][2] = a.y; r[ky][3] = a.z; r[ky][4] = a.w;
      r[ky][5] = q.x; r[ky][6] = q.y; r[ky][7] = q.z; r[ky][8] = q.w;
      r[ky][9] = (yok && rok) ? row[gx0 + 8] : 0.f;
    }
    float lcnv[8], cv[8];
    #pragma unroll
    for (int px = 0; px < 8; ++px) {
      float s = 0.f, s2 = 0.f;
      #pragma unroll
      for (int ky = 0; ky < 3; ++ky)
        #pragma unroll
        for (int kx = 0; kx < 3; ++kx) {
          float v = r[ky][px + kx];
          s += v; s2 = fmaf(v, v, s2);
        }
      float mean = s * (1.f / 9.f);
      float mean2 = s2 * (1.f / 9.f);
      float var = fmaxf(mean2 - mean * mean, 0.f);
      cv[px] = r[1][px + 1];
      lcnv[px] = (cv[px] - mean) * rsqrtf(var + 1e-5f);
    }
    #pragma unroll
    for (int h = 0; h < 2; ++h) {
      float4 o0 = make_float4(lcnv[4*h+0], lcnv[4*h+1], lcnv[4*h+2], lcnv[4*h+3]);
      float4 o1 = make_float4(cv[4*h+0], cv[4*h+1], cv[4*h+2], cv[4*h+3]);
      *reinterpret_cast<float4*>(out + (size_t)c * HWP + p + 4*h) = o0;
      *reinterpret_cast<float4*>(out + (size_t)(3 + c) * HWP + p + 4*h) = o1;
    }
  }
}

// ================= temporal blend: dyn = a*[color,hid] + (1-a)*temporal =================
__global__ __launch_bounds__(256) void blend_v3(const float* __restrict__ color,
                                                const float* __restrict__ hid,
                                                const float* __restrict__ temporal,
                                                const float* __restrict__ alpha,
                                                float* __restrict__ dyn, int first) {
  int i = (blockIdx.x * 256 + threadIdx.x) * 4;
  if (i >= HWP) return;
  if (first) {
    #pragma unroll
    for (int c = 0; c < 3; ++c)
      *reinterpret_cast<float4*>(dyn + (size_t)c * HWP + i) =
          *reinterpret_cast<const float4*>(color + (size_t)c * HWP + i);
    *reinterpret_cast<float4*>(dyn + 3 * (size_t)HWP + i) =
        *reinterpret_cast<const float4*>(hid + i);
  } else {
    float a = alpha[0];
    float om = 1.f - a;
    #pragma unroll
    for (int c = 0; c < 4; ++c) {
      const float* src = (c < 3) ? (color + (size_t)c * HWP) : hid;
      float4 cv = *reinterpret_cast<const float4*>(src + i);
      float4 tv = *reinterpret_cast<const float4*>(temporal + (size_t)c * HWP + i);
      float4 o;
      o.x = a * cv.x + om * tv.x;
      o.y = a * cv.y + om * tv.y;
      o.z = a * cv.z + om * tv.z;
      o.w = a * cv.w + om * tv.w;
      *reinterpret_cast<float4*>(dyn + (size_t)c * HWP + i) = o;
    }
  }
}

// ====== bilateral 7x7 v9: 32x16 tile, 256 thr, 2 px/thread, + precomputed B plane in LDS ======
#define BC 38
#define BR 22
#define BNPX (BC*BR)   // 836
#define BPAD 840

template <bool OUT>
__global__ __launch_bounds__(256, 5) void bilateral_v9(const float* __restrict__ dyn,
                                                       const float* __restrict__ feat,
                                                       const float* __restrict__ scale,
                                                       float* __restrict__ outdyn,
                                                       const float* __restrict__ albedo,
                                                       float* __restrict__ outp) {
  __shared__ uint4  ft[BPAD];
  __shared__ float4 dt[BPAD];
  __shared__ float  bs[BPAD];
  int bx = blockIdx.x % 40;
  int by = blockIdx.x / 40;     // 0..44
  int tid = threadIdx.x;

  float sv[8];
  #pragma unroll
  for (int c = 0; c < 8; ++c) sv[c] = scale[c];

  for (int i = tid; i < BNPX; i += 256) {
    int py = i / BC;
    int px = i - py * BC;
    int gy = min(max(by * 16 + py - 3, 0), HH - 1);
    int gx = min(max(bx * 32 + px - 3, 0), WW - 1);
    size_t g = (size_t)gy * WW + gx;
    int w = bswz(i);
    dt[w] = make_float4(dyn[g], dyn[HWP + g], dyn[2*(size_t)HWP + g], dyn[3*(size_t)HWP + g]);
    uint4 u;
    u.x = pkh(feat[g],                 feat[HWP + g]);
    u.y = pkh(feat[2*(size_t)HWP + g], feat[3*(size_t)HWP + g]);
    u.z = pkh(feat[4*(size_t)HWP + g], feat[5*(size_t)HWP + g]);
    u.w = pkh(feat[6*(size_t)HWP + g], feat[7*(size_t)HWP + g]);
    ft[w] = u;
    // B = sum s*f^2 from the quantized bits (bit-consistent with phase-B's C at the center tap)
    float f[8] = {lo16(u.x), hi16(u.x), lo16(u.y), hi16(u.y),
                  lo16(u.z), hi16(u.z), lo16(u.w), hi16(u.w)};
    float B = 0.f;
    #pragma unroll
    for (int c = 0; c < 8; ++c) B = fmaf(sv[c] * f[c], f[c], B);
    bs[w] = B;
  }
  __syncthreads();

  int txg = tid & 15;   // 2-px group
  int ty  = tid >> 4;   // 0..15

  // center features; sfc = s*fc ; A = bs at center (same bits/op order -> center e == 0 exactly)
  float sfc[2][8], A[2];
  #pragma unroll
  for (int p = 0; p < 2; ++p) {
    int w = bswz((ty + 3) * BC + txg * 2 + 3 + p);
    uint4 u = ft[w];
    float fc[8] = {lo16(u.x), hi16(u.x), lo16(u.y), hi16(u.y),
                   lo16(u.z), hi16(u.z), lo16(u.w), hi16(u.w)};
    #pragma unroll
    for (int c = 0; c < 8; ++c) sfc[p][c] = sv[c] * fc[c];
    A[p] = bs[w];
  }

  float acc[2][4], ws2[2];
  #pragma unroll
  for (int p = 0; p < 2; ++p) {
    ws2[p] = 0.f;
    acc[p][0] = acc[p][1] = acc[p][2] = acc[p][3] = 0.f;
  }

  for (int dy = 0; dy < 7; ++dy) {
    int rowb = (ty + dy) * BC + txg * 2;
    #pragma unroll
    for (int dx = 0; dx < 8; ++dx) {
      int w = bswz(rowb + dx);
      float4 dv = dt[w];
      uint4 u = ft[w];
      float B = bs[w];
      float f[8] = {lo16(u.x), hi16(u.x), lo16(u.y), hi16(u.y),
                    lo16(u.z), hi16(u.z), lo16(u.w), hi16(u.w)};
      #pragma unroll
      for (int p = 0; p < 2; ++p) {
        if (dx - p >= 0 && dx - p <= 6) {   // compile-time pruned
          float C = 0.f;
          #pragma unroll
          for (int c = 0; c < 8; ++c) C = fmaf(sfc[p][c], f[c], C);
          float e = fmaf(-2.f, C, A[p] + B);
          float wgt = __expf(-e);
          acc[p][0] = fmaf(wgt, dv.x, acc[p][0]);
          acc[p][1] = fmaf(wgt, dv.y, acc[p][1]);
          acc[p][2] = fmaf(wgt, dv.z, acc[p][2]);
          acc[p][3] = fmaf(wgt, dv.w, acc[p][3]);
          ws2[p] += wgt;
        }
      }
    }
  }

  int gy = by * 16 + ty;
  int gx0 = bx * 32 + txg * 2;
  size_t p0 = (size_t)gy * WW + gx0;
  float inv0 = 1.f / (ws2[0] + 1e-8f);
  float inv1 = 1.f / (ws2[1] + 1e-8f);
  #pragma unroll
  for (int c = 0; c < 4; ++c) {
    float2 o = make_float2(acc[0][c] * inv0, acc[1][c] * inv1);
    *reinterpret_cast<float2*>(outdyn + (size_t)c * HWP + p0) = o;
    if (OUT && c < 3) {
      float2 al = *reinterpret_cast<const float2*>(albedo + (size_t)c * HWP + p0);
      float2 oo = make_float2(o.x * al.x, o.y * al.y);
      *reinterpret_cast<float2*>(outp + (size_t)c * HWP + p0) = oo;
    }
  }
}

extern "C" void kernel_launch(void* const* d_in, const int* in_sizes, int n_in,
                              void* d_out, int out_size, void* d_ws, size_t ws_size,
                              hipStream_t stream) {
  const float* x          = (const float*)d_in[0];
  const float* alpha      = (const float*)d_in[1];
  const float* cr_w0      = (const float*)d_in[2];
  const float* cr_b0      = (const float*)d_in[3];
  const float* cr_w1      = (const float*)d_in[4];
  const float* cr_b1      = (const float*)d_in[5];
  const float* cr_w2      = (const float*)d_in[6];
  const float* cr_b2      = (const float*)d_in[7];
  const float* hs_w0      = (const float*)d_in[8];
  const float* hs_b0      = (const float*)d_in[9];
  const float* hs_w1      = (const float*)d_in[10];
  const float* hs_b1      = (const float*)d_in[11];
  const float* hs_w2      = (const float*)d_in[12];
  const float* hs_b2      = (const float*)d_in[13];
  const float* filt_w     = (const float*)d_in[14];
  const float* filt_b     = (const float*)d_in[15];
  const float* filt_scale = (const float*)d_in[16];

  float* out = (float*)d_out;
  float* ws  = (float*)d_ws;
  const size_t P = (size_t)HWP;

  bool batched = ws_size >= (size_t)108 * P * sizeof(float);
  float *bufA, *bufB, *dynT, *dynA, *dynB, *hid, *feat;
  if (batched) {
    bufA = ws;            bufB = ws + 48 * P;
    dynT = ws + 96 * P;   dynA = ws + 100 * P;  dynB = ws + 104 * P;
  } else {
    bufA = ws;            bufB = ws + 12 * P;
    dynT = ws + 24 * P;   dynA = ws + 28 * P;   dynB = ws + 32 * P;
  }
  hid  = bufA;   // CNN ping-pong dead by the time hidden is written
  feat = bufB;   // free during filter loop

  const int NB8 = (WW / 128) * (HH / 8);   // 900  (PX=8 lcn, 128 thr)
  const int NBC = (WW / 64)  * (HH / 16);  // 900  (PX=4 conv, 256 thr, tile 64x16)
  const int NBE = HWP / (256 * 4);         // 900
  const int NBB = (WW / 32)  * (HH / 16);  // 1800

  if (batched) {
    dim3 g8(NB8, NFRM), gc(NBC, NFRM);
    lcn_v3<<<g8, 128, 0, stream>>>(x, 12 * P, bufA, 6 * P);
    conv3x3_v4<6, 0, 6,  true ><<<gc, 256, 0, stream>>>(bufA, 6 * P,  nullptr, 0, cr_w0, cr_b0, bufB, 6 * P);
    conv3x3_v4<6, 0, 12, true ><<<gc, 256, 0, stream>>>(bufB, 6 * P,  nullptr, 0, cr_w1, cr_b1, bufA, 12 * P);
    conv3x3_v4<12, 0, 3, false><<<gc, 256, 0, stream>>>(bufA, 12 * P, nullptr, 0, cr_w2, cr_b2, bufB, 3 * P);
    conv3x3_v4<3, 9, 12, true ><<<gc, 256, 0, stream>>>(bufB, 3 * P,  x + 3 * P, 12 * P, hs_w0, hs_b0, bufA, 12 * P);
    conv3x3_v4<12, 0, 12, true><<<gc, 256, 0, stream>>>(bufA, 12 * P, nullptr, 0, hs_w1, hs_b1, bufB, 12 * P);
    conv3x3_v4<12, 0, 1, false><<<gc, 256, 0, stream>>>(bufB, 12 * P, nullptr, 0, hs_w2, hs_b2, hid, P);
  }

  for (int f = 0; f < NFRM; ++f) {
    const float* frame  = x + (size_t)f * 12 * P;
    const float* fixedp = frame + 3 * P;

    if (!batched) {
      dim3 g8(NB8, 1), gc(NBC, 1);
      lcn_v3<<<g8, 128, 0, stream>>>(frame, 0, bufA, 0);
      conv3x3_v4<6, 0, 6,  true ><<<gc, 256, 0, stream>>>(bufA, 0, nullptr, 0, cr_w0, cr_b0, bufB, 0);
      conv3x3_v4<6, 0, 12, true ><<<gc, 256, 0, stream>>>(bufB, 0, nullptr, 0, cr_w1, cr_b1, bufA, 0);
      conv3x3_v4<12, 0, 3, false><<<gc, 256, 0, stream>>>(bufA, 0, nullptr, 0, cr_w2, cr_b2, bufB, 0);
      conv3x3_v4<3, 9, 12, true ><<<gc, 256, 0, stream>>>(bufB, 0, fixedp, 0, hs_w0, hs_b0, bufA, 0);
      conv3x3_v4<12, 0, 12, true><<<gc, 256, 0, stream>>>(bufA, 0, nullptr, 0, hs_w1, hs_b1, bufB, 0);
      conv3x3_v4<12, 0, 1, false><<<gc, 256, 0, stream>>>(bufB, 0, nullptr, 0, hs_w2, hs_b2, hid, 0);
    }

    const float* hidf = batched ? (hid + (size_t)f * P) : hid;
    blend_v3<<<NBE, 256, 0, stream>>>(frame, hidf, dynT, alpha, dynA, f == 0 ? 1 : 0);

    float* cur = dynA;
    float* nxt = dynB;
    for (int k = 0; k < 5; ++k) {
      conv3x3_v4<4, 9, 8, false><<<dim3(NBC, 1), 256, 0, stream>>>(
          cur, 0, fixedp, 0, filt_w + (size_t)k * 8 * 13 * 9, filt_b + k * 8, feat, 0);
      const float* sk = filt_scale + k * 8;
      if (k < 4) {
        bilateral_v9<false><<<NBB, 256, 0, stream>>>(cur, feat, sk, nxt, nullptr, nullptr);
        float* t = cur; cur = nxt; nxt = t;
      } else {
        bilateral_v9<true><<<NBB, 256, 0, stream>>>(cur, feat, sk, dynT,
                                                    fixedp, out + (size_t)f * 3 * P);
      }
    }
  }
}